// Round 2
// baseline (138.177 us; speedup 1.0000x reference)
//
#include <hip/hip_runtime.h>
#include <hip/hip_bf16.h>
#include <stdint.h>

#define N_NODES 40000
#define D_FEAT 64
#define DEG 32
#define E_EDGES (N_NODES * DEG)
#define G_GRAPHS 200
#define NPG 200          // nodes per graph
#define ATT_SZ 64
#define HID 128
#define NCLS 6
#define XS 69            // padded LDS row stride: b128 reads <=2-way banked

__device__ __forceinline__ float selu_f(float x) {
    const float scale = 1.0507009873554805f;
    const float alpha = 1.6732632423543772f;
    return scale * (x > 0.f ? x : alpha * (__expf(x) - 1.f));
}

__device__ __forceinline__ uint32_t f2bf(float f) {   // fp32 -> bf16 bits (RNE)
    uint32_t u = __builtin_bit_cast(uint32_t, f);
    return (u + 0x7fffu + ((u >> 16) & 1u)) >> 16;
}
__device__ __forceinline__ float bflo(uint32_t u) { return __builtin_bit_cast(float, u << 16); }
__device__ __forceinline__ float bfhi(uint32_t u) { return __builtin_bit_cast(float, u & 0xffff0000u); }

// Fused: w = a_vec @ W_att (per-block recompute), P/Q = exp(w.x), y = x @ Wlin^T (bf16-packed).
// R10: 160-node tile, 10x4 microtile -> LDS-pipe cost ~4.5us (measured -3.5us).
// R11: yb is now written as TWO feature-half planes of 64B rows:
//   plane h (h = feat>=32) at yb + h*N*16 u32, row = node*16 u32.
// This lets k_agg bind each XCD's gather to a 2.56MB plane (fits 4MB XCD L2).
// Blocks 0..49 also zero the 200x64 pool (harness poisons ws with 0xAA).
__global__ __launch_bounds__(256) void k_node(const float* __restrict__ x,
                                              const float* __restrict__ Wlin,
                                              const float* __restrict__ Watt,
                                              const float* __restrict__ avec,
                                              float* __restrict__ P,
                                              float* __restrict__ Q,
                                              uint32_t* __restrict__ yb,
                                              float* __restrict__ pool) {
    __shared__ float xs[160 * XS];
    __shared__ float ws[64 * XS];
    __shared__ float ws_w[128];
    int tid = threadIdx.x;
    int n0 = blockIdx.x * 160;
    if (blockIdx.x < 50) pool[blockIdx.x * 256 + tid] = 0.f;

    const float4* x4 = (const float4*)(x + (size_t)n0 * 64);
    const float4* W4 = (const float4*)Wlin;
#pragma unroll
    for (int s = 0; s < 10; ++s) {        // 2560 float4 = 160 rows x 16
        int idx = tid + s * 256, r = idx >> 4, kk = idx & 15;
        *(float4*)&xs[r * XS + kk * 4] = x4[idx];
    }
#pragma unroll
    for (int s = 0; s < 4; ++s) {         // 1024 float4 = 64 rows x 16
        int idx = tid + s * 256, r = idx >> 4, kk = idx & 15;
        *(float4*)&ws[r * XS + kk * 4] = W4[idx];
    }
    if (tid < 128) {                      // w[j] = sum_k avec[k]*Watt[k][j]
        float s = 0.f;
        for (int k = 0; k < ATT_SZ; ++k) s += avec[k] * Watt[k * 128 + tid];
        ws_w[tid] = s;
    }
    __syncthreads();

    if (tid < 160) {                      // P/Q: 1 lane per node, 64 k each
        float s1 = 0.f, s2 = 0.f;
#pragma unroll 8
        for (int k = 0; k < 64; ++k) {
            float xv = xs[tid * XS + k];
            s1 += xv * ws_w[k];
            s2 += xv * ws_w[64 + k];
        }
        P[n0 + tid] = __expf(s1);
        Q[n0 + tid] = __expf(s2);
    }

    int tm = tid >> 4, tf = tid & 15;     // rows tm+16i (i<10), cols 4tf..4tf+3
    int half = tf >> 3, fo = tf & 7;
    uint32_t* plane = yb + (size_t)half * N_NODES * 16;
    float acc[10][4];
#pragma unroll
    for (int i = 0; i < 10; ++i)
#pragma unroll
        for (int j = 0; j < 4; ++j) acc[i][j] = 0.f;
#pragma unroll
    for (int kk = 0; kk < 16; ++kk) {
        float4 wv[4];
#pragma unroll
        for (int j = 0; j < 4; ++j) wv[j] = *(const float4*)&ws[(4 * tf + j) * XS + kk * 4];
#pragma unroll
        for (int i = 0; i < 10; ++i) {
            float4 xv = *(const float4*)&xs[(tm + 16 * i) * XS + kk * 4];
#pragma unroll
            for (int j = 0; j < 4; ++j)
                acc[i][j] += xv.x * wv[j].x + xv.y * wv[j].y
                           + xv.z * wv[j].z + xv.w * wv[j].w;
        }
    }
#pragma unroll
    for (int i = 0; i < 10; ++i) {
        int m = n0 + tm + 16 * i;
        uint32_t p0 = f2bf(acc[i][0]) | (f2bf(acc[i][1]) << 16);
        uint32_t p1 = f2bf(acc[i][2]) | (f2bf(acc[i][3]) << 16);
        *(uint2*)&plane[(size_t)m * 16 + fo * 2] = make_uint2(p0, p1);
    }
}

// V[n] = P[n] / (Q[n] * sum_{e in [32n,32n+32)} P[row[e]])
__global__ __launch_bounds__(256) void k_edges(const int* __restrict__ row,
                                               const float* __restrict__ P,
                                               const float* __restrict__ Q,
                                               float* __restrict__ V) {
    int e = blockIdx.x * 256 + threadIdx.x;
    float p = P[row[e]];
#pragma unroll
    for (int off = 16; off; off >>= 1)
        p += __shfl_xor(p, off, 32);
    if ((threadIdx.x & 31) == 0) {
        int n = e >> 5;
        V[n] = P[n] / (Q[n] * p);
    }
}

// h[n][:] = selu( Q[n]/32 * sum_j V[r_j]*y[r_j][:] + b_lin ), pooled by graph.
// R11: XCD-local gather. Grid = 2500 blocks; block b processes 32 nodes
// (b>>1)*32.. and feature-half (b&1). Blocks round-robin across 8 XCDs
// (blockIdx%8 ~ XCD), so even blocks (XCD 0,2,4,6) touch only plane 0 and odd
// blocks only plane 1: per-XCD gather working set 2.56MB < 4MB L2 -> the 164MB
// logical gather becomes L2-resident instead of thrashing HBM (prev ~6.6TB/s
// effective, ~25us). Rows are 64B: 8 rows x 8 lanes x 8B per wave instruction.
__global__ __launch_bounds__(256) void k_agg(const int* __restrict__ row,
                                             const float* __restrict__ V,
                                             const float* __restrict__ Q,
                                             const uint32_t* __restrict__ yb,
                                             const float* __restrict__ blin,
                                             float* __restrict__ pool) {
    __shared__ float2 meta[1024];        // (V[r], bitcast(r*64))
    int tid = threadIdx.x;
    int nb = blockIdx.x >> 1;            // node block 0..1249
    int half = blockIdx.x & 1;           // feature half: XCD-parity-bound
    int n0 = nb * 32;

    int4 r4 = ((const int4*)(row + (size_t)n0 * 32))[tid];
    meta[4 * tid + 0] = make_float2(V[r4.x], __builtin_bit_cast(float, r4.x << 6));
    meta[4 * tid + 1] = make_float2(V[r4.y], __builtin_bit_cast(float, r4.y << 6));
    meta[4 * tid + 2] = make_float2(V[r4.z], __builtin_bit_cast(float, r4.z << 6));
    meta[4 * tid + 3] = make_float2(V[r4.w], __builtin_bit_cast(float, r4.w << 6));
    __syncthreads();

    int wv = tid >> 6, lane = tid & 63;
    int sr = lane >> 3, fi = lane & 7;   // sr: row-slot (8 rows/instr), fi: 8B chunk
    float4 bl4 = ((const float4*)blin)[half * 8 + fi];
    int nw0 = n0 + wv * 8;               // 8 aligned nodes: one graph (8 | 200)
    float4 pacc = make_float4(0.f, 0.f, 0.f, 0.f);
    const char* ybc = (const char*)yb + (size_t)half * (N_NODES * 64);
#pragma unroll 1
    for (int nn = 0; nn < 8; ++nn) {
        int n = nw0 + nn;
        int base = (wv * 8 + nn) * 32;
        float4 a = make_float4(0.f, 0.f, 0.f, 0.f);
#pragma unroll
        for (int s = 0; s < 4; ++s) {
            float2 m = meta[base + s * 8 + sr];
            uint32_t rbyte = __builtin_bit_cast(uint32_t, m.y);
            uint2 u = *(const uint2*)(ybc + rbyte + fi * 8);
            a.x += m.x * bflo(u.x);
            a.y += m.x * bfhi(u.x);
            a.z += m.x * bflo(u.y);
            a.w += m.x * bfhi(u.y);
        }
        a.x += __shfl_xor(a.x, 8, 64); a.x += __shfl_xor(a.x, 16, 64); a.x += __shfl_xor(a.x, 32, 64);
        a.y += __shfl_xor(a.y, 8, 64); a.y += __shfl_xor(a.y, 16, 64); a.y += __shfl_xor(a.y, 32, 64);
        a.z += __shfl_xor(a.z, 8, 64); a.z += __shfl_xor(a.z, 16, 64); a.z += __shfl_xor(a.z, 32, 64);
        a.w += __shfl_xor(a.w, 8, 64); a.w += __shfl_xor(a.w, 16, 64); a.w += __shfl_xor(a.w, 32, 64);
        float qn = Q[n] * (1.f / 32.f);
        pacc.x += selu_f(qn * a.x + bl4.x);
        pacc.y += selu_f(qn * a.y + bl4.y);
        pacc.z += selu_f(qn * a.z + bl4.z);
        pacc.w += selu_f(qn * a.w + bl4.w);
    }
    if (sr == 0) {
        int g = nw0 / NPG;
        float* pp = &pool[g * 64 + half * 32 + 4 * fi];
        atomicAdd(pp + 0, pacc.x);
        atomicAdd(pp + 1, pacc.y);
        atomicAdd(pp + 2, pacc.z);
        atomicAdd(pp + 3, pacc.w);
    }
}

// pooled = pool/200; hcls = selu(W1 @ pooled + b1); logits = W2 @ hcls + b2; softmax
__global__ __launch_bounds__(128) void k_cls(const float* __restrict__ pool,
                                             const float* __restrict__ W1,
                                             const float* __restrict__ b1,
                                             const float* __restrict__ W2,
                                             const float* __restrict__ b2,
                                             float* __restrict__ out) {
    __shared__ float ps[64];
    __shared__ float hc[HID];
    __shared__ float lg[NCLS];
    int t = threadIdx.x, g = blockIdx.x;
    if (t < 64) ps[t] = pool[g * 64 + t] * (1.f / NPG);
    __syncthreads();
    float s = b1[t];
    const float4* w14 = (const float4*)(W1 + t * 64);
    const float4* ps4 = (const float4*)ps;
#pragma unroll
    for (int kk = 0; kk < 16; ++kk) {
        float4 w = w14[kk], p = ps4[kk];
        s += w.x * p.x; s += w.y * p.y; s += w.z * p.z; s += w.w * p.w;
    }
    hc[t] = selu_f(s);
    __syncthreads();
    if (t < NCLS) {
        float l = b2[t];
        const float4* w24 = (const float4*)(W2 + t * 128);
        const float4* hc4 = (const float4*)hc;
        for (int kk = 0; kk < 32; ++kk) {
            float4 w = w24[kk], h = hc4[kk];
            l += w.x * h.x; l += w.y * h.y; l += w.z * h.z; l += w.w * h.w;
        }
        lg[t] = l;
    }
    __syncthreads();
    if (t == 0) {
        float m = lg[0];
        for (int c = 1; c < NCLS; ++c) m = fmaxf(m, lg[c]);
        float ex[NCLS], sum = 0.f;
        for (int c = 0; c < NCLS; ++c) { ex[c] = __expf(lg[c] - m); sum += ex[c]; }
        for (int c = 0; c < NCLS; ++c) out[g * NCLS + c] = ex[c] / sum;
    }
}

extern "C" void kernel_launch(void* const* d_in, const int* in_sizes, int n_in,
                              void* d_out, int out_size, void* d_ws, size_t ws_size,
                              hipStream_t stream) {
    const float* x    = (const float*)d_in[0];
    const float* Wlin = (const float*)d_in[1];
    const float* blin = (const float*)d_in[2];
    const float* Watt = (const float*)d_in[3];
    const float* avec = (const float*)d_in[4];
    const float* W1   = (const float*)d_in[5];
    const float* b1   = (const float*)d_in[6];
    const float* W2   = (const float*)d_in[7];
    const float* b2   = (const float*)d_in[8];
    const int*   row  = (const int*)d_in[9];   // edge_index[0]; edge_index[1] is structured
    float* out = (float*)d_out;

    // ws layout: P[N] | Q[N] | V[N] | pool[200*64] | yb[2 planes x N*16 u32 (bf16x2 y)]
    float* P    = (float*)d_ws;
    float* Q    = P + N_NODES;
    float* V    = Q + N_NODES;
    float* pool = V + N_NODES;
    uint32_t* yb = (uint32_t*)(pool + G_GRAPHS * 64);

    k_node<<<N_NODES / 160, 256, 0, stream>>>(x, Wlin, Watt, avec, P, Q, yb, pool);
    k_edges<<<E_EDGES / 256, 256, 0, stream>>>(row, P, Q, V);
    k_agg<<<(N_NODES / 32) * 2, 256, 0, stream>>>(row, V, Q, yb, blin, pool);
    k_cls<<<G_GRAPHS, 128, 0, stream>>>(pool, W1, b1, W2, b2, out);
}

// Round 4
// 136.939 us; speedup vs baseline: 1.0090x; 1.0090x over previous
//
#include <hip/hip_runtime.h>
#include <hip/hip_bf16.h>
#include <stdint.h>

#define N_NODES 40000
#define D_FEAT 64
#define DEG 32
#define E_EDGES (N_NODES * DEG)
#define G_GRAPHS 200
#define NPG 200          // nodes per graph
#define ATT_SZ 64
#define HID 128
#define NCLS 6
#define XS 69            // padded LDS row stride: b128 reads <=2-way banked

__device__ __forceinline__ float selu_f(float x) {
    const float scale = 1.0507009873554805f;
    const float alpha = 1.6732632423543772f;
    return scale * (x > 0.f ? x : alpha * (__expf(x) - 1.f));
}

__device__ __forceinline__ uint32_t f2bf(float f) {   // fp32 -> bf16 bits (RNE)
    uint32_t u = __builtin_bit_cast(uint32_t, f);
    return (u + 0x7fffu + ((u >> 16) & 1u)) >> 16;
}
__device__ __forceinline__ float bflo(uint32_t u) { return __builtin_bit_cast(float, u << 16); }
__device__ __forceinline__ float bfhi(uint32_t u) { return __builtin_bit_cast(float, u & 0xffff0000u); }

// Fused: w = a_vec @ W_att (per-block recompute), P/Q = exp(w.x), y = x @ Wlin^T (bf16-packed).
// R12/R13: rocprof R11 exposed k_node at ~52us with VALUBusy 6.8%, HBM 2.5%,
// occupancy 10% -> wave-starved (250 blocks x 4 waves = 1 wave/SIMD; zero latency
// hiding). Fix: same 160-node tile / LDS / summation order, but 512 threads, 5x4
// microtile: per-thread serial chain halves, resident waves double (8/CU). Stores
// unchanged per-wave (4 consecutive rows x 16 cols). yb stays two 64B-row planes
// for k_agg's XCD-L2 binding. Blocks 0..24 zero the 200x64 pool (ws poisoned 0xAA).
// (R13 = R12 resubmit: container infra failure, kernel never ran.)
__global__ __launch_bounds__(512) void k_node(const float* __restrict__ x,
                                              const float* __restrict__ Wlin,
                                              const float* __restrict__ Watt,
                                              const float* __restrict__ avec,
                                              float* __restrict__ P,
                                              float* __restrict__ Q,
                                              uint32_t* __restrict__ yb,
                                              float* __restrict__ pool) {
    __shared__ float xs[160 * XS];
    __shared__ float ws[64 * XS];
    __shared__ float ws_w[128];
    int tid = threadIdx.x;
    int n0 = blockIdx.x * 160;
    if (blockIdx.x < 25) pool[blockIdx.x * 512 + tid] = 0.f;

    const float4* x4 = (const float4*)(x + (size_t)n0 * 64);
    const float4* W4 = (const float4*)Wlin;
#pragma unroll
    for (int s = 0; s < 5; ++s) {         // 2560 float4 = 160 rows x 16
        int idx = tid + s * 512, r = idx >> 4, kk = idx & 15;
        *(float4*)&xs[r * XS + kk * 4] = x4[idx];
    }
#pragma unroll
    for (int s = 0; s < 2; ++s) {         // 1024 float4 = 64 rows x 16
        int idx = tid + s * 512, r = idx >> 4, kk = idx & 15;
        *(float4*)&ws[r * XS + kk * 4] = W4[idx];
    }
    if (tid < 128) {                      // w[j] = sum_k avec[k]*Watt[k][j]
        float s = 0.f;
        for (int k = 0; k < ATT_SZ; ++k) s += avec[k] * Watt[k * 128 + tid];
        ws_w[tid] = s;
    }
    __syncthreads();

    if (tid < 160) {                      // P/Q: 1 lane per node, 64 k each
        float s1 = 0.f, s2 = 0.f;
#pragma unroll 8
        for (int k = 0; k < 64; ++k) {
            float xv = xs[tid * XS + k];
            s1 += xv * ws_w[k];
            s2 += xv * ws_w[64 + k];
        }
        P[n0 + tid] = __expf(s1);
        Q[n0 + tid] = __expf(s2);
    }

    int tm = tid >> 4, tf = tid & 15;     // rows tm+32i (i<5), cols 4tf..4tf+3
    int half = tf >> 3, fo = tf & 7;
    uint32_t* plane = yb + (size_t)half * N_NODES * 16;
    float acc[5][4];
#pragma unroll
    for (int i = 0; i < 5; ++i)
#pragma unroll
        for (int j = 0; j < 4; ++j) acc[i][j] = 0.f;
#pragma unroll
    for (int kk = 0; kk < 16; ++kk) {
        float4 wv[4];
#pragma unroll
        for (int j = 0; j < 4; ++j) wv[j] = *(const float4*)&ws[(4 * tf + j) * XS + kk * 4];
#pragma unroll
        for (int i = 0; i < 5; ++i) {
            float4 xv = *(const float4*)&xs[(tm + 32 * i) * XS + kk * 4];
#pragma unroll
            for (int j = 0; j < 4; ++j)
                acc[i][j] += xv.x * wv[j].x + xv.y * wv[j].y
                           + xv.z * wv[j].z + xv.w * wv[j].w;
        }
    }
#pragma unroll
    for (int i = 0; i < 5; ++i) {
        int m = n0 + tm + 32 * i;
        uint32_t p0 = f2bf(acc[i][0]) | (f2bf(acc[i][1]) << 16);
        uint32_t p1 = f2bf(acc[i][2]) | (f2bf(acc[i][3]) << 16);
        *(uint2*)&plane[(size_t)m * 16 + fo * 2] = make_uint2(p0, p1);
    }
}

// V[n] = P[n] / (Q[n] * sum_{e in [32n,32n+32)} P[row[e]])
__global__ __launch_bounds__(256) void k_edges(const int* __restrict__ row,
                                               const float* __restrict__ P,
                                               const float* __restrict__ Q,
                                               float* __restrict__ V) {
    int e = blockIdx.x * 256 + threadIdx.x;
    float p = P[row[e]];
#pragma unroll
    for (int off = 16; off; off >>= 1)
        p += __shfl_xor(p, off, 32);
    if ((threadIdx.x & 31) == 0) {
        int n = e >> 5;
        V[n] = P[n] / (Q[n] * p);
    }
}

// h[n][:] = selu( Q[n]/32 * sum_j V[r_j]*y[r_j][:] + b_lin ), pooled by graph.
// R11: XCD-local gather (unchanged). Grid = 2500 blocks; block b processes
// 32 nodes (b>>1)*32.. and feature-half (b&1). Blocks round-robin across 8 XCDs
// (blockIdx%8 ~ XCD): even blocks touch only plane 0, odd only plane 1 ->
// per-XCD gather working set 2.56MB < 4MB L2. Rows are 64B: 8 rows x 8 lanes x 8B
// per wave instruction.
__global__ __launch_bounds__(256) void k_agg(const int* __restrict__ row,
                                             const float* __restrict__ V,
                                             const float* __restrict__ Q,
                                             const uint32_t* __restrict__ yb,
                                             const float* __restrict__ blin,
                                             float* __restrict__ pool) {
    __shared__ float2 meta[1024];        // (V[r], bitcast(r*64))
    int tid = threadIdx.x;
    int nb = blockIdx.x >> 1;            // node block 0..1249
    int half = blockIdx.x & 1;           // feature half: XCD-parity-bound
    int n0 = nb * 32;

    int4 r4 = ((const int4*)(row + (size_t)n0 * 32))[tid];
    meta[4 * tid + 0] = make_float2(V[r4.x], __builtin_bit_cast(float, r4.x << 6));
    meta[4 * tid + 1] = make_float2(V[r4.y], __builtin_bit_cast(float, r4.y << 6));
    meta[4 * tid + 2] = make_float2(V[r4.z], __builtin_bit_cast(float, r4.z << 6));
    meta[4 * tid + 3] = make_float2(V[r4.w], __builtin_bit_cast(float, r4.w << 6));
    __syncthreads();

    int wv = tid >> 6, lane = tid & 63;
    int sr = lane >> 3, fi = lane & 7;   // sr: row-slot (8 rows/instr), fi: 8B chunk
    float4 bl4 = ((const float4*)blin)[half * 8 + fi];
    int nw0 = n0 + wv * 8;               // 8 aligned nodes: one graph (8 | 200)
    float4 pacc = make_float4(0.f, 0.f, 0.f, 0.f);
    const char* ybc = (const char*)yb + (size_t)half * (N_NODES * 64);
#pragma unroll 1
    for (int nn = 0; nn < 8; ++nn) {
        int n = nw0 + nn;
        int base = (wv * 8 + nn) * 32;
        float4 a = make_float4(0.f, 0.f, 0.f, 0.f);
#pragma unroll
        for (int s = 0; s < 4; ++s) {
            float2 m = meta[base + s * 8 + sr];
            uint32_t rbyte = __builtin_bit_cast(uint32_t, m.y);
            uint2 u = *(const uint2*)(ybc + rbyte + fi * 8);
            a.x += m.x * bflo(u.x);
            a.y += m.x * bfhi(u.x);
            a.z += m.x * bflo(u.y);
            a.w += m.x * bfhi(u.y);
        }
        a.x += __shfl_xor(a.x, 8, 64); a.x += __shfl_xor(a.x, 16, 64); a.x += __shfl_xor(a.x, 32, 64);
        a.y += __shfl_xor(a.y, 8, 64); a.y += __shfl_xor(a.y, 16, 64); a.y += __shfl_xor(a.y, 32, 64);
        a.z += __shfl_xor(a.z, 8, 64); a.z += __shfl_xor(a.z, 16, 64); a.z += __shfl_xor(a.z, 32, 64);
        a.w += __shfl_xor(a.w, 8, 64); a.w += __shfl_xor(a.w, 16, 64); a.w += __shfl_xor(a.w, 32, 64);
        float qn = Q[n] * (1.f / 32.f);
        pacc.x += selu_f(qn * a.x + bl4.x);
        pacc.y += selu_f(qn * a.y + bl4.y);
        pacc.z += selu_f(qn * a.z + bl4.z);
        pacc.w += selu_f(qn * a.w + bl4.w);
    }
    if (sr == 0) {
        int g = nw0 / NPG;
        float* pp = &pool[g * 64 + half * 32 + 4 * fi];
        atomicAdd(pp + 0, pacc.x);
        atomicAdd(pp + 1, pacc.y);
        atomicAdd(pp + 2, pacc.z);
        atomicAdd(pp + 3, pacc.w);
    }
}

// pooled = pool/200; hcls = selu(W1 @ pooled + b1); logits = W2 @ hcls + b2; softmax
__global__ __launch_bounds__(128) void k_cls(const float* __restrict__ pool,
                                             const float* __restrict__ W1,
                                             const float* __restrict__ b1,
                                             const float* __restrict__ W2,
                                             const float* __restrict__ b2,
                                             float* __restrict__ out) {
    __shared__ float ps[64];
    __shared__ float hc[HID];
    __shared__ float lg[NCLS];
    int t = threadIdx.x, g = blockIdx.x;
    if (t < 64) ps[t] = pool[g * 64 + t] * (1.f / NPG);
    __syncthreads();
    float s = b1[t];
    const float4* w14 = (const float4*)(W1 + t * 64);
    const float4* ps4 = (const float4*)ps;
#pragma unroll
    for (int kk = 0; kk < 16; ++kk) {
        float4 w = w14[kk], p = ps4[kk];
        s += w.x * p.x; s += w.y * p.y; s += w.z * p.z; s += w.w * p.w;
    }
    hc[t] = selu_f(s);
    __syncthreads();
    if (t < NCLS) {
        float l = b2[t];
        const float4* w24 = (const float4*)(W2 + t * 128);
        const float4* hc4 = (const float4*)hc;
        for (int kk = 0; kk < 32; ++kk) {
            float4 w = w24[kk], h = hc4[kk];
            l += w.x * h.x; l += w.y * h.y; l += w.z * h.z; l += w.w * h.w;
        }
        lg[t] = l;
    }
    __syncthreads();
    if (t == 0) {
        float m = lg[0];
        for (int c = 1; c < NCLS; ++c) m = fmaxf(m, lg[c]);
        float ex[NCLS], sum = 0.f;
        for (int c = 0; c < NCLS; ++c) { ex[c] = __expf(lg[c] - m); sum += ex[c]; }
        for (int c = 0; c < NCLS; ++c) out[g * NCLS + c] = ex[c] / sum;
    }
}

extern "C" void kernel_launch(void* const* d_in, const int* in_sizes, int n_in,
                              void* d_out, int out_size, void* d_ws, size_t ws_size,
                              hipStream_t stream) {
    const float* x    = (const float*)d_in[0];
    const float* Wlin = (const float*)d_in[1];
    const float* blin = (const float*)d_in[2];
    const float* Watt = (const float*)d_in[3];
    const float* avec = (const float*)d_in[4];
    const float* W1   = (const float*)d_in[5];
    const float* b1   = (const float*)d_in[6];
    const float* W2   = (const float*)d_in[7];
    const float* b2   = (const float*)d_in[8];
    const int*   row  = (const int*)d_in[9];   // edge_index[0]; edge_index[1] is structured
    float* out = (float*)d_out;

    // ws layout: P[N] | Q[N] | V[N] | pool[200*64] | yb[2 planes x N*16 u32 (bf16x2 y)]
    float* P    = (float*)d_ws;
    float* Q    = P + N_NODES;
    float* V    = Q + N_NODES;
    float* pool = V + N_NODES;
    uint32_t* yb = (uint32_t*)(pool + G_GRAPHS * 64);

    k_node<<<N_NODES / 160, 512, 0, stream>>>(x, Wlin, Watt, avec, P, Q, yb, pool);
    k_edges<<<E_EDGES / 256, 256, 0, stream>>>(row, P, Q, V);
    k_agg<<<(N_NODES / 32) * 2, 256, 0, stream>>>(row, V, Q, yb, blin, pool);
    k_cls<<<G_GRAPHS, 128, 0, stream>>>(pool, W1, b1, W2, b2, out);
}

// Round 6
// 129.079 us; speedup vs baseline: 1.0705x; 1.0609x over previous
//
#include <hip/hip_runtime.h>
#include <hip/hip_bf16.h>
#include <stdint.h>

#define N_NODES 40000
#define D_FEAT 64
#define DEG 32
#define E_EDGES (N_NODES * DEG)
#define G_GRAPHS 200
#define NPG 200          // nodes per graph
#define ATT_SZ 64
#define HID 128
#define NCLS 6
#define XS 69            // padded LDS row stride: b128 reads <=2-way banked

__device__ __forceinline__ float selu_f(float x) {
    const float scale = 1.0507009873554805f;
    const float alpha = 1.6732632423543772f;
    return scale * (x > 0.f ? x : alpha * (__expf(x) - 1.f));
}

__device__ __forceinline__ uint32_t f2bf(float f) {   // fp32 -> bf16 bits (RNE)
    uint32_t u = __builtin_bit_cast(uint32_t, f);
    return (u + 0x7fffu + ((u >> 16) & 1u)) >> 16;
}
__device__ __forceinline__ float bflo(uint32_t u) { return __builtin_bit_cast(float, u << 16); }
__device__ __forceinline__ float bfhi(uint32_t u) { return __builtin_bit_cast(float, u & 0xffff0000u); }

// Fused: w = a_vec @ W_att (per-block recompute), P/Q = exp(w.x), y = x @ Wlin^T (bf16-packed).
// R15: I-FETCH THEORY. rocprof R11 measured k_node=52us with VALU 6.8%, HBM 2.5%,
// LDS conflicts ~0, occupancy-doubling (R13) nearly ineffective -> no execution
// pipe accounts for the time. The fully-unrolled kk loop is ~3000 straight-line
// instrs (~24KB code), executed once per block from a cold L1I: waves stall on
// cold instruction lines (~100-200cy per 64B/8-instr line) -> ~40us/block of
// I-fetch serialization that no PMC in our set exposes. Fix: #pragma unroll 2
// on the kk loop (body ~3KB, loops 8x, I$-resident after iter 1). Same
// summation order -> bit-identical y. Everything else reverted to R10 (130.5us
// best: 160-node tile, 256thr, single-plane 128B yb rows).
// Blocks 0..49 zero the 200x64 pool (harness poisons ws with 0xAA).
__global__ __launch_bounds__(256) void k_node(const float* __restrict__ x,
                                              const float* __restrict__ Wlin,
                                              const float* __restrict__ Watt,
                                              const float* __restrict__ avec,
                                              float* __restrict__ P,
                                              float* __restrict__ Q,
                                              uint32_t* __restrict__ yb,
                                              float* __restrict__ pool) {
    __shared__ float xs[160 * XS];
    __shared__ float ws[64 * XS];
    __shared__ float ws_w[128];
    int tid = threadIdx.x;
    int n0 = blockIdx.x * 160;
    if (blockIdx.x < 50) pool[blockIdx.x * 256 + tid] = 0.f;

    const float4* x4 = (const float4*)(x + (size_t)n0 * 64);
    const float4* W4 = (const float4*)Wlin;
#pragma unroll
    for (int s = 0; s < 10; ++s) {        // 2560 float4 = 160 rows x 16
        int idx = tid + s * 256, r = idx >> 4, kk = idx & 15;
        *(float4*)&xs[r * XS + kk * 4] = x4[idx];
    }
#pragma unroll
    for (int s = 0; s < 4; ++s) {         // 1024 float4 = 64 rows x 16
        int idx = tid + s * 256, r = idx >> 4, kk = idx & 15;
        *(float4*)&ws[r * XS + kk * 4] = W4[idx];
    }
    if (tid < 128) {                      // w[j] = sum_k avec[k]*Watt[k][j]
        float s = 0.f;
        for (int k = 0; k < ATT_SZ; ++k) s += avec[k] * Watt[k * 128 + tid];
        ws_w[tid] = s;
    }
    __syncthreads();

    if (tid < 160) {                      // P/Q: 1 lane per node, 64 k each
        float s1 = 0.f, s2 = 0.f;
#pragma unroll 8
        for (int k = 0; k < 64; ++k) {
            float xv = xs[tid * XS + k];
            s1 += xv * ws_w[k];
            s2 += xv * ws_w[64 + k];
        }
        P[n0 + tid] = __expf(s1);
        Q[n0 + tid] = __expf(s2);
    }

    int tm = tid >> 4, tf = tid & 15;     // rows tm+16i (i<10), cols 4tf..4tf+3
    float acc[10][4];
#pragma unroll
    for (int i = 0; i < 10; ++i)
#pragma unroll
        for (int j = 0; j < 4; ++j) acc[i][j] = 0.f;
#pragma unroll 2                          // R15: keep body ~3KB -> I$-resident loop
    for (int kk = 0; kk < 16; ++kk) {
        float4 wv[4];
#pragma unroll
        for (int j = 0; j < 4; ++j) wv[j] = *(const float4*)&ws[(4 * tf + j) * XS + kk * 4];
#pragma unroll
        for (int i = 0; i < 10; ++i) {
            float4 xv = *(const float4*)&xs[(tm + 16 * i) * XS + kk * 4];
#pragma unroll
            for (int j = 0; j < 4; ++j)
                acc[i][j] += xv.x * wv[j].x + xv.y * wv[j].y
                           + xv.z * wv[j].z + xv.w * wv[j].w;
        }
    }
#pragma unroll
    for (int i = 0; i < 10; ++i) {
        int m = n0 + tm + 16 * i;
        uint32_t p0 = f2bf(acc[i][0]) | (f2bf(acc[i][1]) << 16);
        uint32_t p1 = f2bf(acc[i][2]) | (f2bf(acc[i][3]) << 16);
        *(uint2*)&yb[(size_t)m * 32 + tf * 2] = make_uint2(p0, p1);
    }
}

// V[n] = P[n] / (Q[n] * sum_{e in [32n,32n+32)} P[row[e]])
__global__ __launch_bounds__(256) void k_edges(const int* __restrict__ row,
                                               const float* __restrict__ P,
                                               const float* __restrict__ Q,
                                               float* __restrict__ V) {
    int e = blockIdx.x * 256 + threadIdx.x;
    float p = P[row[e]];
#pragma unroll
    for (int off = 16; off; off >>= 1)
        p += __shfl_xor(p, off, 32);
    if ((threadIdx.x & 31) == 0) {
        int n = e >> 5;
        V[n] = P[n] / (Q[n] * p);
    }
}

// h[n][:] = selu( Q[n]/32 * sum_j V[r_j]*y[r_j][:] + b_lin ), pooled by graph.
// Block = 32 nodes. 1024 edge records (V[r], r*128) staged in LDS. Wave: 8 nodes;
// quarter q gathers row s*4+q as uint2 (16 lanes x 8B = 128B row; 4 rows/instr).
// Serialized node loop (unroll 1): measured best — small I-footprint + the kernel
// sits at the random-gather BW ceiling (R3 fp32: 327MB/48.7us; R6 bf16: 164MB/~25us).
__global__ __launch_bounds__(256) void k_agg(const int* __restrict__ row,
                                             const float* __restrict__ V,
                                             const float* __restrict__ Q,
                                             const uint32_t* __restrict__ yb,
                                             const float* __restrict__ blin,
                                             float* __restrict__ pool) {
    __shared__ float2 meta[1024];        // (V[r], bitcast(r*128))
    int tid = threadIdx.x;
    int n0 = blockIdx.x * 32;

    int4 r4 = ((const int4*)(row + (size_t)n0 * 32))[tid];
    meta[4 * tid + 0] = make_float2(V[r4.x], __builtin_bit_cast(float, r4.x << 7));
    meta[4 * tid + 1] = make_float2(V[r4.y], __builtin_bit_cast(float, r4.y << 7));
    meta[4 * tid + 2] = make_float2(V[r4.z], __builtin_bit_cast(float, r4.z << 7));
    meta[4 * tid + 3] = make_float2(V[r4.w], __builtin_bit_cast(float, r4.w << 7));
    __syncthreads();

    int wv = tid >> 6, lane = tid & 63;
    int q = lane >> 4, fi = lane & 15;
    float4 bl4 = ((const float4*)blin)[fi];
    int nw0 = n0 + wv * 8;               // 8 aligned nodes: one graph (8 | 200)
    float4 pacc = make_float4(0.f, 0.f, 0.f, 0.f);
    const char* ybc = (const char*)yb;
#pragma unroll 1
    for (int nn = 0; nn < 8; ++nn) {
        int n = nw0 + nn;
        int base = (wv * 8 + nn) * 32;
        float4 a = make_float4(0.f, 0.f, 0.f, 0.f);
#pragma unroll
        for (int s = 0; s < 8; ++s) {
            float2 m = meta[base + s * 4 + q];
            uint32_t rbyte = __builtin_bit_cast(uint32_t, m.y);
            uint2 u = *(const uint2*)(ybc + rbyte + fi * 8);
            a.x += m.x * bflo(u.x);
            a.y += m.x * bfhi(u.x);
            a.z += m.x * bflo(u.y);
            a.w += m.x * bfhi(u.y);
        }
        a.x += __shfl_xor(a.x, 16, 64); a.x += __shfl_xor(a.x, 32, 64);
        a.y += __shfl_xor(a.y, 16, 64); a.y += __shfl_xor(a.y, 32, 64);
        a.z += __shfl_xor(a.z, 16, 64); a.z += __shfl_xor(a.z, 32, 64);
        a.w += __shfl_xor(a.w, 16, 64); a.w += __shfl_xor(a.w, 32, 64);
        float qn = Q[n] * (1.f / 32.f);
        pacc.x += selu_f(qn * a.x + bl4.x);
        pacc.y += selu_f(qn * a.y + bl4.y);
        pacc.z += selu_f(qn * a.z + bl4.z);
        pacc.w += selu_f(qn * a.w + bl4.w);
    }
    if (q == 0) {
        int g = nw0 / NPG;
        float* pp = &pool[g * 64 + 4 * fi];
        atomicAdd(pp + 0, pacc.x);
        atomicAdd(pp + 1, pacc.y);
        atomicAdd(pp + 2, pacc.z);
        atomicAdd(pp + 3, pacc.w);
    }
}

// pooled = pool/200; hcls = selu(W1 @ pooled + b1); logits = W2 @ hcls + b2; softmax
__global__ __launch_bounds__(128) void k_cls(const float* __restrict__ pool,
                                             const float* __restrict__ W1,
                                             const float* __restrict__ b1,
                                             const float* __restrict__ W2,
                                             const float* __restrict__ b2,
                                             float* __restrict__ out) {
    __shared__ float ps[64];
    __shared__ float hc[HID];
    __shared__ float lg[NCLS];
    int t = threadIdx.x, g = blockIdx.x;
    if (t < 64) ps[t] = pool[g * 64 + t] * (1.f / NPG);
    __syncthreads();
    float s = b1[t];
    const float4* w14 = (const float4*)(W1 + t * 64);
    const float4* ps4 = (const float4*)ps;
#pragma unroll
    for (int kk = 0; kk < 16; ++kk) {
        float4 w = w14[kk], p = ps4[kk];
        s += w.x * p.x; s += w.y * p.y; s += w.z * p.z; s += w.w * p.w;
    }
    hc[t] = selu_f(s);
    __syncthreads();
    if (t < NCLS) {
        float l = b2[t];
        const float4* w24 = (const float4*)(W2 + t * 128);
        const float4* hc4 = (const float4*)hc;
        for (int kk = 0; kk < 32; ++kk) {
            float4 w = w24[kk], h = hc4[kk];
            l += w.x * h.x; l += w.y * h.y; l += w.z * h.z; l += w.w * h.w;
        }
        lg[t] = l;
    }
    __syncthreads();
    if (t == 0) {
        float m = lg[0];
        for (int c = 1; c < NCLS; ++c) m = fmaxf(m, lg[c]);
        float ex[NCLS], sum = 0.f;
        for (int c = 0; c < NCLS; ++c) { ex[c] = __expf(lg[c] - m); sum += ex[c]; }
        for (int c = 0; c < NCLS; ++c) out[g * NCLS + c] = ex[c] / sum;
    }
}

extern "C" void kernel_launch(void* const* d_in, const int* in_sizes, int n_in,
                              void* d_out, int out_size, void* d_ws, size_t ws_size,
                              hipStream_t stream) {
    const float* x    = (const float*)d_in[0];
    const float* Wlin = (const float*)d_in[1];
    const float* blin = (const float*)d_in[2];
    const float* Watt = (const float*)d_in[3];
    const float* avec = (const float*)d_in[4];
    const float* W1   = (const float*)d_in[5];
    const float* b1   = (const float*)d_in[6];
    const float* W2   = (const float*)d_in[7];
    const float* b2   = (const float*)d_in[8];
    const int*   row  = (const int*)d_in[9];   // edge_index[0]; edge_index[1] is structured
    float* out = (float*)d_out;

    // ws layout: P[N] | Q[N] | V[N] | pool[200*64] | yb[N*32 u32 (bf16x2 y, 128B rows)]
    float* P    = (float*)d_ws;
    float* Q    = P + N_NODES;
    float* V    = Q + N_NODES;
    float* pool = V + N_NODES;
    uint32_t* yb = (uint32_t*)(pool + G_GRAPHS * 64);

    k_node<<<N_NODES / 160, 256, 0, stream>>>(x, Wlin, Watt, avec, P, Q, yb, pool);
    k_edges<<<E_EDGES / 256, 256, 0, stream>>>(row, P, Q, V);
    k_agg<<<N_NODES / 32, 256, 0, stream>>>(row, V, Q, yb, blin, pool);
    k_cls<<<G_GRAPHS, 128, 0, stream>>>(pool, W1, b1, W2, b2, out);
}